// Round 7
// baseline (90.935 us; speedup 1.0000x reference)
//
#include <hip/hip_runtime.h>
#include <math.h>

#define B_  2048
#define H_  256
#define IN_ 64

typedef __attribute__((ext_vector_type(8))) short bf8_t;   // 8 x bf16 (4 VGPR)
typedef __attribute__((ext_vector_type(4))) short s4_t;
typedef __attribute__((ext_vector_type(4))) float f4_t;

#define MFMA_BF16(a, b, c) __builtin_amdgcn_mfma_f32_16x16x32_bf16((a), (b), (c), 0, 0, 0)

__device__ __forceinline__ short f2bf(float f) {         // rne
  union { float f; unsigned u; } v; v.f = f;
  unsigned u = v.u + 0x7fffu + ((v.u >> 16) & 1u);
  return (short)(u >> 16);
}
__device__ __forceinline__ float bf2f(short s) {
  union { unsigned u; float f; } v; v.u = ((unsigned)(unsigned short)s) << 16;
  return v.f;
}

// Pre-split weights in MFMA B-fragment layout: element j of fragment
// [(g*NKS+ks)*64+lane] is W[c][k], c = g*16 + (lane&15), k = ks*32 + (lane>>4)*8 + j.
__device__ __align__(16) short g_whf[2][65536];   // [hi/lo] 256x256
__device__ __align__(16) short g_wof[2][65536];   // [hi/lo] 256x256
__device__ __align__(16) short g_wxf[2][16384];   // [hi/lo] 256x64

__global__ void prep_frag(const float* __restrict__ wh, const float* __restrict__ wo,
                          const float* __restrict__ wx) {
  int tid = blockIdx.x * 256 + threadIdx.x;       // 72*256 = 18432
  const float* W; short* Dh; short* Dl; int ld, ksh, o8;
  if (tid < 8192)       { W = wh; Dh = g_whf[0]; Dl = g_whf[1]; ld = 256; ksh = 3; o8 = tid; }
  else if (tid < 16384) { W = wo; Dh = g_wof[0]; Dl = g_wof[1]; ld = 256; ksh = 3; o8 = tid - 8192; }
  else if (tid < 18432) { W = wx; Dh = g_wxf[0]; Dl = g_wxf[1]; ld = 64;  ksh = 1; o8 = tid - 16384; }
  else return;
  int lane = o8 & 63;
  int gks = o8 >> 6;
  int g = gks >> ksh, ks = gks & ((1 << ksh) - 1);
  int c = g * 16 + (lane & 15);
  int k0 = ks * 32 + ((lane >> 4) & 3) * 8;
  const float* p = W + (size_t)c * ld + k0;
  bf8_t hi, lo;
#pragma unroll
  for (int j = 0; j < 8; ++j) {
    float f = p[j];
    short h = f2bf(f);
    hi[j] = h; lo[j] = f2bf(f - bf2f(h));
  }
  *reinterpret_cast<bf8_t*>(Dh + (size_t)o8 * 8) = hi;
  *reinterpret_cast<bf8_t*>(Dl + (size_t)o8 * 8) = lo;
}

// Single-tile GEMMs (wave owns 16 cols); odd/even-ks partial acc for 2-chain ILP.
#define GEMM3s(A0, AH, AL, WH, WL, NK) do {                                     \
  f4_t q0 = {0.f,0.f,0.f,0.f};                                                  \
  _Pragma("unroll")                                                             \
  for (int ks = 0; ks < (NK); ++ks) {                                           \
    bf8_t ah = *reinterpret_cast<const bf8_t*>(&AH[ln][ks * 32 + lq * 8]);      \
    bf8_t al = *reinterpret_cast<const bf8_t*>(&AL[ln][ks * 32 + lq * 8]);      \
    if (ks & 1) {                                                               \
      q0 = MFMA_BF16(ah, WH[ks], q0); q0 = MFMA_BF16(ah, WL[ks], q0);           \
      q0 = MFMA_BF16(al, WH[ks], q0);                                           \
    } else {                                                                    \
      A0 = MFMA_BF16(ah, WH[ks], A0); A0 = MFMA_BF16(ah, WL[ks], A0);           \
      A0 = MFMA_BF16(al, WH[ks], A0);                                           \
    }                                                                           \
  }                                                                             \
  A0 = A0 + q0; } while (0)

#define GEMM2s(A0, AH, AL, WH, NK) do {                                         \
  f4_t q0 = {0.f,0.f,0.f,0.f};                                                  \
  _Pragma("unroll")                                                             \
  for (int ks = 0; ks < (NK); ++ks) {                                           \
    bf8_t ah = *reinterpret_cast<const bf8_t*>(&AH[ln][ks * 32 + lq * 8]);      \
    bf8_t al = *reinterpret_cast<const bf8_t*>(&AL[ln][ks * 32 + lq * 8]);      \
    if (ks & 1) { q0 = MFMA_BF16(ah, WH[ks], q0); q0 = MFMA_BF16(al, WH[ks], q0); } \
    else        { A0 = MFMA_BF16(ah, WH[ks], A0); A0 = MFMA_BF16(al, WH[ks], A0); } \
  }                                                                             \
  A0 = A0 + q0; } while (0)

#define GEMM1s(A0, AH, WH, NK) do {                                             \
  f4_t q0 = {0.f,0.f,0.f,0.f};                                                  \
  _Pragma("unroll")                                                             \
  for (int ks = 0; ks < (NK); ++ks) {                                           \
    bf8_t ah = *reinterpret_cast<const bf8_t*>(&AH[ln][ks * 32 + lq * 8]);      \
    if (ks & 1) q0 = MFMA_BF16(ah, WH[ks], q0);                                 \
    else        A0 = MFMA_BF16(ah, WH[ks], A0);                                 \
  }                                                                             \
  A0 = A0 + q0; } while (0)

__global__ __launch_bounds__(1024, 4) void jacde_mfma(
    const float* __restrict__ h_g, const float* __restrict__ x_g,
    const float* __restrict__ xd_g, const float* __restrict__ wx,
    const float* __restrict__ wh, const float* __restrict__ b0,
    const float* __restrict__ b1, float* __restrict__ out) {

  __shared__ short h_hi[16][264], h_lo[16][264];
  __shared__ short x_hi[16][72],  x_lo[16][72];
  __shared__ short xd_hi[16][72], xd_lo[16][72];
  __shared__ short u_hi[16][264], u_lo[16][264];
  __shared__ short v_hi[16][264];
  __shared__ float l1_t[16][264];
  __shared__ int   fix_cnt;
  __shared__ int   fix_list[64];

  const int tid  = threadIdx.x;
  const int wv   = tid >> 6;        // wave 0..15
  const int lane = tid & 63;
  const int ln   = lane & 15;       // A row / C col-within-tile
  const int lq   = lane >> 4;       // quad
  const int r0   = blockIdx.x * 16; // batch-row base
  const int cbase = wv * 16;        // wave's 16-column group

  if (tid == 0) fix_cnt = 0;

  // ---- stage activations to split-bf16 LDS (1024 threads: h in one pass) ----
  {
    int r = tid >> 6, k4 = (tid & 63) * 4;
    f4_t v = *reinterpret_cast<const f4_t*>(h_g + (size_t)(r0 + r) * H_ + k4);
    s4_t shv, slv;
#pragma unroll
    for (int j = 0; j < 4; ++j) { short h = f2bf(v[j]); shv[j] = h; slv[j] = f2bf(v[j] - bf2f(h)); }
    *reinterpret_cast<s4_t*>(&h_hi[r][k4]) = shv;
    *reinterpret_cast<s4_t*>(&h_lo[r][k4]) = slv;
  }
  if (tid < 512) {
    int t2 = tid & 255;
    const float* src = (tid < 256) ? x_g : xd_g;
    short (*dh)[72] = (tid < 256) ? x_hi : xd_hi;
    short (*dl)[72] = (tid < 256) ? x_lo : xd_lo;
    int r = t2 >> 4, k4 = (t2 & 15) * 4;
    f4_t v = *reinterpret_cast<const f4_t*>(src + (size_t)(r0 + r) * IN_ + k4);
    s4_t shv, slv;
#pragma unroll
    for (int j = 0; j < 4; ++j) { short h = f2bf(v[j]); shv[j] = h; slv[j] = f2bf(v[j] - bf2f(h)); }
    *reinterpret_cast<s4_t*>(&dh[r][k4]) = shv;
    *reinterpret_cast<s4_t*>(&dl[r][k4]) = slv;
  }

  // ---- persistent weight-hi fragments (live through all GEMM steps) ----
  bf8_t whf[8], wof[8];
  f4_t acc0, sacc0;
  float dre0[4], dta0[4], hd0[4];

  // ---- stage 1: l1 = x@wx^T + h@wh^T + b0 (3-term);  s = xdot@wx^T (3-term) ----
  {
    bf8_t whl[8], wxh[2], wxl[2];
#pragma unroll
    for (int ks = 0; ks < 8; ++ks) {
      int off = ((wv * 8 + ks) * 64 + lane) * 8;
      whf[ks] = *reinterpret_cast<const bf8_t*>(&g_whf[0][off]);
      whl[ks] = *reinterpret_cast<const bf8_t*>(&g_whf[1][off]);
    }
#pragma unroll
    for (int ks = 0; ks < 2; ++ks) {
      int off = ((wv * 2 + ks) * 64 + lane) * 8;
      wxh[ks] = *reinterpret_cast<const bf8_t*>(&g_wxf[0][off]);
      wxl[ks] = *reinterpret_cast<const bf8_t*>(&g_wxf[1][off]);
    }
    __syncthreads();   // activations staged

    float bv0 = b0[cbase + ln];
    acc0 = (f4_t){bv0, bv0, bv0, bv0};
    GEMM3s(acc0, h_hi, h_lo, whf, whl, 8);
    GEMM3s(acc0, x_hi, x_lo, wxh, wxl, 2);
    sacc0 = (f4_t){0.f, 0.f, 0.f, 0.f};
    GEMM3s(sacc0, xd_hi, xd_lo, wxh, wxl, 2);
#pragma unroll
    for (int r = 0; r < 4; ++r)   // C/D: col=lane&15, row=quad*4+reg [m89]
      l1_t[lq * 4 + r][cbase + ln] = acc0[r];
  }
  __syncthreads();

  // ---- fp64 fixup of near-zero l1 (hard relu gate must match fp64 anchor) ----
  for (int e = tid; e < 16 * 256; e += 1024) {
    int r = e >> 8, c = e & 255;
    if (fabsf(l1_t[r][c]) < 1e-4f) {
      int idx = atomicAdd(&fix_cnt, 1);
      if (idx < 64) fix_list[idx] = (r << 8) | c;
    }
  }
  __syncthreads();
  {
    int nfix = min(fix_cnt, 64);
    for (int e = wv; e < nfix; e += 16) {
      int rc = fix_list[e];
      int r = rc >> 8, c = rc & 255;
      const float* hrow = h_g + (size_t)(r0 + r) * H_;
      const float* wrow = wh + (size_t)c * H_;
      double sum = (double)hrow[lane]       * (double)wrow[lane]
                 + (double)hrow[lane + 64]  * (double)wrow[lane + 64]
                 + (double)hrow[lane + 128] * (double)wrow[lane + 128]
                 + (double)hrow[lane + 192] * (double)wrow[lane + 192]
                 + (double)x_g[(size_t)(r0 + r) * IN_ + lane] * (double)wx[(size_t)c * IN_ + lane];
#pragma unroll
      for (int m = 32; m; m >>= 1) sum += __shfl_xor(sum, m);
      if (lane == 0) l1_t[r][c] = (float)(sum + (double)b0[c]);
    }
  }
  __syncthreads();

  // ---- gates: relu_val (split) to u bufs; dre into registers at wave positions ----
  for (int e = tid; e < 16 * 256; e += 1024) {
    int r = e >> 8, c = e & 255;
    float l1 = l1_t[r][c];
    float rv = l1 > 0.f ? l1 : 0.f;
    short hi = f2bf(rv);
    u_hi[r][c] = hi;
    u_lo[r][c] = f2bf(rv - bf2f(hi));
  }
#pragma unroll
  for (int r = 0; r < 4; ++r)
    dre0[r] = (l1_t[lq * 4 + r][cbase + ln] > 0.f) ? 1.f : 0.f;
  __syncthreads();

  // ---- stage 2: lout = relu@wout^T + b1 (3-term) -> dtanh ----
  {
    bf8_t wol[8];
#pragma unroll
    for (int ks = 0; ks < 8; ++ks) {
      int off = ((wv * 8 + ks) * 64 + lane) * 8;
      wof[ks] = *reinterpret_cast<const bf8_t*>(&g_wof[0][off]);
      wol[ks] = *reinterpret_cast<const bf8_t*>(&g_wof[1][off]);
    }
    float bv0 = b1[cbase + ln];
    acc0 = (f4_t){bv0, bv0, bv0, bv0};
    GEMM3s(acc0, u_hi, u_lo, wof, wol, 8);
#pragma unroll
    for (int r = 0; r < 4; ++r) {
      float t0 = tanhf(acc0[r]);
      dta0[r] = 1.f - t0 * t0;
    }
  }
  __syncthreads();   // all waves done reading relu from u bufs

  // ---- u0 = dre * s (split write at wave positions) ----
#pragma unroll
  for (int r = 0; r < 4; ++r) {
    int row = lq * 4 + r;
    float v0 = dre0[r] * sacc0[r];
    short h0 = f2bf(v0);
    u_hi[row][cbase + ln] = h0;
    u_lo[row][cbase + ln] = f2bf(v0 - bf2f(h0));
  }
  __syncthreads();

  // ---- jx = dta * (u0@wout^T): h_dot = jx, curr -> v_hi (2-term: largest term) ----
  acc0 = (f4_t){0.f, 0.f, 0.f, 0.f};
  GEMM2s(acc0, u_hi, u_lo, wof, 8);
#pragma unroll
  for (int r = 0; r < 4; ++r) {
    int row = lq * 4 + r;
    float v0 = dta0[r] * acc0[r];
    hd0[r] = v0;
    v_hi[row][cbase + ln] = f2bf(v0);
  }
  __syncthreads();

  // ---- 8x 1-term chain: curr <- dta*((dre*(curr@wh^T))@wout^T); h_dot += curr ----
  for (int it = 0; it < 8; ++it) {
    acc0 = (f4_t){0.f, 0.f, 0.f, 0.f};
    GEMM1s(acc0, v_hi, whf, 8);
#pragma unroll
    for (int r = 0; r < 4; ++r)
      u_hi[lq * 4 + r][cbase + ln] = f2bf(dre0[r] * acc0[r]);
    __syncthreads();

    acc0 = (f4_t){0.f, 0.f, 0.f, 0.f};
    GEMM1s(acc0, u_hi, wof, 8);
#pragma unroll
    for (int r = 0; r < 4; ++r) {
      float v0 = dta0[r] * acc0[r];
      hd0[r] += v0;
      if (it < 7) v_hi[lq * 4 + r][cbase + ln] = f2bf(v0);
    }
    __syncthreads();
  }

  // ---- epilogue: fp32 out ----
#pragma unroll
  for (int r = 0; r < 4; ++r)
    out[(size_t)(r0 + lq * 4 + r) * H_ + cbase + ln] = hd0[r];
}

extern "C" void kernel_launch(void* const* d_in, const int* in_sizes, int n_in,
                              void* d_out, int out_size, void* d_ws, size_t ws_size,
                              hipStream_t stream) {
  const float* h_g  = (const float*)d_in[0];
  const float* x_g  = (const float*)d_in[1];
  const float* xd_g = (const float*)d_in[2];
  const float* wx   = (const float*)d_in[3];
  const float* wh   = (const float*)d_in[4];
  const float* wo   = (const float*)d_in[5];
  const float* b0   = (const float*)d_in[6];
  const float* b1   = (const float*)d_in[7];
  prep_frag<<<dim3(72), dim3(256), 0, stream>>>(wh, wo, wx);
  jacde_mfma<<<dim3(B_ / 16), dim3(1024), 0, stream>>>(
      h_g, x_g, xd_g, wx, wh, b0, b1, (float*)d_out);
}